// Round 9
// baseline (925.514 us; speedup 1.0000x reference)
//
#include <hip/hip_runtime.h>
#include <hip/hip_bf16.h>

#define NVOX 200000
#define NTAP 27
#define OSTR 68     // out LDS row stride (floats)
#define WSTR 1088   // per-wave LDS region (dwords): nbr 432 ints / out 16x68 floats
#define ROWB 128    // bytes per bf16 feature row (64 ch)

typedef __bf16          bf16x8 __attribute__((ext_vector_type(8)));
typedef unsigned short  u16x8  __attribute__((ext_vector_type(8)));
typedef float           f32x4  __attribute__((ext_vector_type(4)));

// ws layout (bytes). fbuf/hbuf have NVOX+1 rows; row NVOX is the zero
// sentinel so gathers are branchless (and invalid lanes hit one L1-hot line).
#define FB_BYTES    ((size_t)(NVOX + 1) * ROWB)      // 25,600,128
#define WSHUF_BYTES (NTAP * 2 * 4 * 64 * 16)         // 221,184 per conv
#define FB_OFF      0
#define H_OFF       (FB_BYTES)
#define WS1_OFF     (2 * FB_BYTES)
#define WS2_OFF     (WS1_OFF + WSHUF_BYTES)
#define FLAG_OFF    (WS2_OFF + WSHUF_BYTES)

static __device__ __forceinline__ unsigned short f2bf_bits(float f) {
    __hip_bfloat16 h = __float2bfloat16(f);
    union { __hip_bfloat16 h; unsigned short u; } u; u.h = h; return u.u;
}
static __device__ __forceinline__ float bf2f(unsigned short s) {
    union { float f; unsigned u; } u; u.u = ((unsigned)s) << 16; return u.f;
}
static __device__ __forceinline__ float ld_param(const void* p, int c, int isbf) {
    return isbf ? bf2f(((const unsigned short*)p)[c]) : ((const float*)p)[c];
}
static __device__ __forceinline__ bf16x8 asbf(uint4 v) {
    union { uint4 q; bf16x8 b; } u; u.q = v; return u.b;
}
// wave-uniform: are float tensors packed bf16? (v1 in [0.5,1.5] -> 0x3F00..0x3FC0)
static __device__ __forceinline__ int wave_isbf(const unsigned* v1w) {
    int l = threadIdx.x & 63;
    int ok = 1;
    if (l < 32) {
        unsigned w = v1w[l], lo = w & 0xFFFFu, hi = w >> 16;
        ok = (lo >= 0x3F00u && lo <= 0x3FC0u && hi >= 0x3F00u && hi <= 0x3FC0u);
    }
    return __all(ok);
}

// -------- mega-prep: feats->bf16 fbuf (blocks 0..6249), W-shuffle
// (6250..6357), flags + sentinel-row zeroing (6358)
__global__ __launch_bounds__(256)
void prep_kernel(const void* __restrict__ feats,
                 const void* __restrict__ W1, const void* __restrict__ W2,
                 const unsigned* __restrict__ v1w, const unsigned* __restrict__ nbrw,
                 uint4* __restrict__ fbuf, uint4* __restrict__ hbuf,
                 uint4* __restrict__ Ws1, uint4* __restrict__ Ws2,
                 int* __restrict__ flags) {
    const int bx = blockIdx.x;
    if (bx < 6250) {
        const int isbf = wave_isbf(v1w);
        size_t t = (size_t)bx * 256 + threadIdx.x;   // fragment id (16 B)
        if (isbf) {
            fbuf[t] = ((const uint4*)feats)[t];
        } else {
            float4 a = ((const float4*)feats)[2 * t];
            float4 b = ((const float4*)feats)[2 * t + 1];
            union { uint4 q; unsigned short u[8]; } o;
            o.u[0] = f2bf_bits(a.x); o.u[1] = f2bf_bits(a.y);
            o.u[2] = f2bf_bits(a.z); o.u[3] = f2bf_bits(a.w);
            o.u[4] = f2bf_bits(b.x); o.u[5] = f2bf_bits(b.y);
            o.u[6] = f2bf_bits(b.z); o.u[7] = f2bf_bits(b.w);
            fbuf[t] = o.q;
        }
    } else if (bx < 6358) {
        const int isbf = wave_isbf(v1w);
        int t = (bx - 6250) * 256 + threadIdx.x;     // < 27648
        const void* W = (t < 13824) ? W1 : W2;
        uint4* Ws     = (t < 13824) ? Ws1 : Ws2;
        int f = (t < 13824) ? t : t - 13824;
        int k  = f / 512;
        int r  = f % 512;
        int kc = r / 256;
        int r2 = r % 256;
        int nc = r2 / 64;
        int l  = r2 % 64;
        int quad = l >> 4, li = l & 15;
        unsigned short tmp[8];
#pragma unroll
        for (int j = 0; j < 8; ++j) {
            int off = k * 4096 + (kc * 32 + quad * 8 + j) * 64 + (nc * 16 + li);
            tmp[j] = isbf ? ((const unsigned short*)W)[off]
                          : f2bf_bits(((const float*)W)[off]);
        }
        uint4 v;
        v.x = (unsigned)tmp[0] | ((unsigned)tmp[1] << 16);
        v.y = (unsigned)tmp[2] | ((unsigned)tmp[3] << 16);
        v.z = (unsigned)tmp[4] | ((unsigned)tmp[5] << 16);
        v.w = (unsigned)tmp[6] | ((unsigned)tmp[7] << 16);
        Ws[f] = v;
    } else {
        int t = threadIdx.x;
        if (t < 64) {
            int isbf = wave_isbf(v1w);
            int n64ok = 1;
#pragma unroll
            for (int i = 0; i < 8; ++i)   // int64 nbr: every odd dword zero
                if (nbrw[2 * (t * 8 + i) + 1] != 0u) n64ok = 0;
            int n64 = __all(n64ok);
            if (t == 0) { flags[0] = isbf; flags[1] = n64; }
        }
        uint4 z = make_uint4(0u, 0u, 0u, 0u);
        if (t >= 64 && t < 72) fbuf[(size_t)NVOX * 8 + (t - 64)] = z;
        if (t >= 72 && t < 80) hbuf[(size_t)NVOX * 8 + (t - 72)] = z;
    }
}

// prefetch tap kk: A-frags are direct per-lane 16B gathers in MFMA layout;
// B-frags are coalesced 16B loads from shuffled Ws. All into named registers.
// NOTE: variadic forwarding layer so XSET/YSET expand before arg binding.
#define PF(...) PF_(__VA_ARGS__)
#define PF_(kk, A0, A1, B0, B1, B2, B3, B4, B5, B6, B7) do {                \
    int idx_ = nbrW[(l & 15) * NTAP + (kk)];                                \
    const uint4* rp_ = (const uint4*)(srcB + (size_t)idx_ * ROWB);          \
    A0 = rp_[quad]; A1 = rp_[quad + 4];                                     \
    const uint4* wp_ = Ws + (kk) * 512 + l;                                 \
    B0 = wp_[0];   B1 = wp_[256];                                           \
    B2 = wp_[64];  B3 = wp_[320];                                           \
    B4 = wp_[128]; B5 = wp_[384];                                           \
    B6 = wp_[192]; B7 = wp_[448];                                           \
} while (0)

// 8 MFMAs of one tap: 4 cout-slices x 2 K-chunks
#define DOMF(...) DOMF_(__VA_ARGS__)
#define DOMF_(A0, A1, B0, B1, B2, B3, B4, B5, B6, B7) do {                  \
    acc0 = __builtin_amdgcn_mfma_f32_16x16x32_bf16(asbf(A0), asbf(B0), acc0, 0, 0, 0); \
    acc1 = __builtin_amdgcn_mfma_f32_16x16x32_bf16(asbf(A0), asbf(B2), acc1, 0, 0, 0); \
    acc2 = __builtin_amdgcn_mfma_f32_16x16x32_bf16(asbf(A0), asbf(B4), acc2, 0, 0, 0); \
    acc3 = __builtin_amdgcn_mfma_f32_16x16x32_bf16(asbf(A0), asbf(B6), acc3, 0, 0, 0); \
    acc0 = __builtin_amdgcn_mfma_f32_16x16x32_bf16(asbf(A1), asbf(B1), acc0, 0, 0, 0); \
    acc1 = __builtin_amdgcn_mfma_f32_16x16x32_bf16(asbf(A1), asbf(B3), acc1, 0, 0, 0); \
    acc2 = __builtin_amdgcn_mfma_f32_16x16x32_bf16(asbf(A1), asbf(B5), acc2, 0, 0, 0); \
    acc3 = __builtin_amdgcn_mfma_f32_16x16x32_bf16(asbf(A1), asbf(B7), acc3, 0, 0, 0); \
} while (0)

#define XSET XA0, XA1, XB0, XB1, XB2, XB3, XB4, XB5, XB6, XB7
#define YSET YA0, YA1, YB0, YB1, YB2, YB3, YB4, YB5, YB6, YB7

// -------- fused sparse-conv + BN (+ residual) + ReLU, wave-private.
// Block: 4 independent waves; wave w owns rows [base+16w, base+16w+16) x all
// 64 couts. No __syncthreads in the K-loop (no cross-wave data). Compacted
// wave-uniform tap loop iterates only active taps (avg ~15 of 27).
__global__ __launch_bounds__(256, 4)
void conv_bn_kernel(const uint4* __restrict__ srcV,   // (NVOX+1) x 8 uint4 bf16 rows
                    const void* __restrict__ nbr,
                    const uint4* __restrict__ Ws,
                    const void* __restrict__ gg, const void* __restrict__ bb,
                    const void* __restrict__ mm, const void* __restrict__ vv,
                    const u16x8* __restrict__ resid,  // bf16 fbuf rows, null for conv1
                    const int* __restrict__ flags,
                    void* __restrict__ dst, int final_out) {
    __shared__ int smi[4 * WSTR];        // 4 wave-private regions (17.4 KB)
    const int tid  = threadIdx.x;
    const int w    = tid >> 6, l = tid & 63;
    const int quad = l >> 4, li = l & 15;
    const int base = blockIdx.x * 64;
    const int wrow = base + w * 16;      // this wave's first row
    const int isbf = flags[0];
    const int n64  = flags[1];
    int* nbrW = smi + w * WSTR;          // [16 rows][27 taps], row-major
    const char* srcB = (const char*)srcV;

    // stage this wave's 16x27 nbr indices (coalesced copy, wave-local LDS)
    if (!n64) {
        const int* np = (const int*)nbr + (long)wrow * NTAP;
        for (int i = l; i < 16 * NTAP; i += 64) nbrW[i] = np[i];
    } else {
        const long long* np = (const long long*)nbr + (long)wrow * NTAP;
        for (int i = l; i < 16 * NTAP; i += 64) nbrW[i] = (int)np[i];
    }

    // wave-uniform active-tap bitmask (lockstep wave: LDS write->read is safe)
    unsigned msk = 0;
    for (int t = 0; t < NTAP; ++t) {
        int idx = nbrW[(l & 15) * NTAP + t];
        if (__any(idx < NVOX)) msk |= 1u << t;
    }

    f32x4 acc0 = {0.f, 0.f, 0.f, 0.f}, acc1 = {0.f, 0.f, 0.f, 0.f};
    f32x4 acc2 = {0.f, 0.f, 0.f, 0.f}, acc3 = {0.f, 0.f, 0.f, 0.f};
    uint4 XA0, XA1, XB0, XB1, XB2, XB3, XB4, XB5, XB6, XB7;
    uint4 YA0, YA1, YB0, YB1, YB2, YB3, YB4, YB5, YB6, YB7;

    // compacted tap loop, X/Y register double-buffer (all branches uniform)
    unsigned mrem = msk;                 // center tap always set -> mrem != 0
    int ka = __ffs(mrem) - 1; mrem &= mrem - 1;
    PF(ka, XSET);
    for (;;) {
        int kb = -1;
        if (mrem) { kb = __ffs(mrem) - 1; mrem &= mrem - 1; }
        if (kb < 0) { DOMF(XSET); break; }
        PF(kb, YSET);
        DOMF(XSET);
        int kc = -1;
        if (mrem) { kc = __ffs(mrem) - 1; mrem &= mrem - 1; }
        if (kc < 0) { DOMF(YSET); break; }
        PF(kc, XSET);
        DOMF(YSET);
    }

    // BN params for this lane's 4 channels (one per cout-slice)
    float scl[4], ofs[4];
#pragma unroll
    for (int s = 0; s < 4; ++s) {
        int c = s * 16 + li;
        scl[s] = ld_param(gg, c, isbf) * rsqrtf(ld_param(vv, c, isbf) + 1e-5f);
        ofs[s] = ld_param(bb, c, isbf) - ld_param(mm, c, isbf) * scl[s];
    }

    // wave-local transpose through own LDS region (aliases nbrW, dead now)
    float* outW = (float*)nbrW;
#define EPI(s, accv) do { _Pragma("unroll")                                 \
    for (int r = 0; r < 4; ++r)                                             \
        outW[(quad * 4 + r) * OSTR + (s) * 16 + li] = accv[r] * scl[s] + ofs[s]; \
    } while (0)
    EPI(0, acc0); EPI(1, acc1); EPI(2, acc2); EPI(3, acc3);
#undef EPI

    // coalesced writeout: lane l -> row l>>2, 16-channel chunk l&3
    {
        int trow = l >> 2, cc = l & 3;
        long grow = wrow + trow;
        const float4* lp = (const float4*)&outW[trow * OSTR + cc * 16];
        float4 q0 = lp[0], q1 = lp[1], q2 = lp[2], q3 = lp[3];
        float vals[16] = {q0.x, q0.y, q0.z, q0.w, q1.x, q1.y, q1.z, q1.w,
                          q2.x, q2.y, q2.z, q2.w, q3.x, q3.y, q3.z, q3.w};

        if (resid) {
            const u16x8* rp = resid + grow * 8 + cc * 2;
            u16x8 r0v = rp[0], r1v = rp[1];
#pragma unroll
            for (int j = 0; j < 8; ++j) { vals[j] += bf2f(r0v[j]); vals[8 + j] += bf2f(r1v[j]); }
        }
#pragma unroll
        for (int j = 0; j < 16; ++j) vals[j] = fmaxf(vals[j], 0.f);

        const int store_bf = (!final_out) || isbf;
        if (store_bf) {
            u16x8 o0, o1;
#pragma unroll
            for (int j = 0; j < 8; ++j) { o0[j] = f2bf_bits(vals[j]); o1[j] = f2bf_bits(vals[8 + j]); }
            u16x8* dp = (u16x8*)dst + grow * 8 + cc * 2;
            dp[0] = o0; dp[1] = o1;
        } else {
            float4* dp = (float4*)dst + grow * 16 + cc * 4;
            dp[0] = (float4){vals[0], vals[1], vals[2], vals[3]};
            dp[1] = (float4){vals[4], vals[5], vals[6], vals[7]};
            dp[2] = (float4){vals[8], vals[9], vals[10], vals[11]};
            dp[3] = (float4){vals[12], vals[13], vals[14], vals[15]};
        }
    }
}

extern "C" void kernel_launch(void* const* d_in, const int* in_sizes, int n_in,
                              void* d_out, int out_size, void* d_ws, size_t ws_size,
                              hipStream_t stream) {
    const void* feats = d_in[0];
    const void* nbr   = d_in[1];
    const void* W1    = d_in[2];
    const void* g1    = d_in[3];
    const void* b1    = d_in[4];
    const void* m1    = d_in[5];
    const void* v1    = d_in[6];
    const void* W2    = d_in[7];
    const void* g2    = d_in[8];
    const void* b2    = d_in[9];
    const void* m2    = d_in[10];
    const void* v2    = d_in[11];

    char* ws = (char*)d_ws;
    uint4* fbuf = (uint4*)(ws + FB_OFF);
    uint4* hbuf = (uint4*)(ws + H_OFF);
    uint4* Ws1  = (uint4*)(ws + WS1_OFF);
    uint4* Ws2  = (uint4*)(ws + WS2_OFF);
    int*   flags = (int*)(ws + FLAG_OFF);

    prep_kernel<<<dim3(6359), dim3(256), 0, stream>>>(
        feats, W1, W2, (const unsigned*)v1, (const unsigned*)nbr,
        fbuf, hbuf, Ws1, Ws2, flags);

    conv_bn_kernel<<<dim3(NVOX / 64), dim3(256), 0, stream>>>(
        fbuf, nbr, Ws1, g1, b1, m1, v1,
        /*resid=*/nullptr, flags, hbuf, /*final_out=*/0);

    conv_bn_kernel<<<dim3(NVOX / 64), dim3(256), 0, stream>>>(
        hbuf, nbr, Ws2, g2, b2, m2, v2,
        /*resid=*/(const u16x8*)fbuf, flags, d_out, /*final_out=*/1);
}

// Round 11
// 291.812 us; speedup vs baseline: 3.1716x; 3.1716x over previous
//
#include <hip/hip_runtime.h>
#include <hip/hip_bf16.h>

#define NVOX 200000
#define NTAP 27
#define NSTR 68   // nbr LDS row stride (ints)
#define OSTR 68   // out LDS row stride (floats)
#define ROWB 128  // bytes per bf16 feature row (64 ch)

typedef __bf16          bf16x8 __attribute__((ext_vector_type(8)));
typedef unsigned short  u16x8  __attribute__((ext_vector_type(8)));
typedef float           f32x4  __attribute__((ext_vector_type(4)));

// ws layout (bytes). fbuf/hbuf have NVOX+1 rows; row NVOX is the zero
// sentinel so gathers are branchless.
#define FB_BYTES    ((size_t)(NVOX + 1) * ROWB)      // 25,600,128
#define WSHUF_BYTES (NTAP * 2 * 4 * 64 * 16)         // 221,184 per conv
#define FB_OFF      0
#define H_OFF       (FB_BYTES)
#define WS1_OFF     (2 * FB_BYTES)
#define WS2_OFF     (WS1_OFF + WSHUF_BYTES)
#define FLAG_OFF    (WS2_OFF + WSHUF_BYTES + 32768)  // pad: clamp-read safety

static __device__ __forceinline__ unsigned short f2bf_bits(float f) {
    __hip_bfloat16 h = __float2bfloat16(f);
    union { __hip_bfloat16 h; unsigned short u; } u; u.h = h; return u.u;
}
static __device__ __forceinline__ float bf2f(unsigned short s) {
    union { float f; unsigned u; } u; u.u = ((unsigned)s) << 16; return u.f;
}
static __device__ __forceinline__ float ld_param(const void* p, int c, int isbf) {
    return isbf ? bf2f(((const unsigned short*)p)[c]) : ((const float*)p)[c];
}
// async DMA: 16 B from global (per-lane addr) -> LDS (wave-uniform base + lane*16)
static __device__ __forceinline__ void gload_lds16(const void* gp, void* lp) {
    __builtin_amdgcn_global_load_lds(
        (const __attribute__((address_space(1))) void*)gp,
        (__attribute__((address_space(3))) void*)lp, 16, 0, 0);
}
// wave-uniform: are float tensors packed bf16? (v1 in [0.5,1.5] -> 0x3F00..0x3FC0)
static __device__ __forceinline__ int wave_isbf(const unsigned* v1w) {
    int l = threadIdx.x & 63;
    int ok = 1;
    if (l < 32) {
        unsigned w = v1w[l], lo = w & 0xFFFFu, hi = w >> 16;
        ok = (lo >= 0x3F00u && lo <= 0x3FC0u && hi >= 0x3F00u && hi <= 0x3FC0u);
    }
    return __all(ok);
}

// -------- mega-prep: feats->bf16 fbuf (blocks 0..6249), W-shuffle
// (6250..6357), flags + sentinel-row zeroing (6358)
__global__ __launch_bounds__(256)
void prep_kernel(const void* __restrict__ feats,
                 const void* __restrict__ W1, const void* __restrict__ W2,
                 const unsigned* __restrict__ v1w, const unsigned* __restrict__ nbrw,
                 uint4* __restrict__ fbuf, uint4* __restrict__ hbuf,
                 uint4* __restrict__ Ws1, uint4* __restrict__ Ws2,
                 int* __restrict__ flags) {
    const int bx = blockIdx.x;
    if (bx < 6250) {
        const int isbf = wave_isbf(v1w);
        size_t t = (size_t)bx * 256 + threadIdx.x;   // fragment id (16 B)
        if (isbf) {
            fbuf[t] = ((const uint4*)feats)[t];
        } else {
            float4 a = ((const float4*)feats)[2 * t];
            float4 b = ((const float4*)feats)[2 * t + 1];
            union { uint4 q; unsigned short u[8]; } o;
            o.u[0] = f2bf_bits(a.x); o.u[1] = f2bf_bits(a.y);
            o.u[2] = f2bf_bits(a.z); o.u[3] = f2bf_bits(a.w);
            o.u[4] = f2bf_bits(b.x); o.u[5] = f2bf_bits(b.y);
            o.u[6] = f2bf_bits(b.z); o.u[7] = f2bf_bits(b.w);
            fbuf[t] = o.q;
        }
    } else if (bx < 6358) {
        const int isbf = wave_isbf(v1w);
        int t = (bx - 6250) * 256 + threadIdx.x;     // < 27648
        const void* W = (t < 13824) ? W1 : W2;
        uint4* Ws     = (t < 13824) ? Ws1 : Ws2;
        int f = (t < 13824) ? t : t - 13824;
        int k  = f / 512;
        int r  = f % 512;
        int kc = r / 256;
        int r2 = r % 256;
        int nc = r2 / 64;
        int l  = r2 % 64;
        int quad = l >> 4, li = l & 15;
        unsigned short tmp[8];
#pragma unroll
        for (int j = 0; j < 8; ++j) {
            int off = k * 4096 + (kc * 32 + quad * 8 + j) * 64 + (nc * 16 + li);
            tmp[j] = isbf ? ((const unsigned short*)W)[off]
                          : f2bf_bits(((const float*)W)[off]);
        }
        uint4 v;
        v.x = (unsigned)tmp[0] | ((unsigned)tmp[1] << 16);
        v.y = (unsigned)tmp[2] | ((unsigned)tmp[3] << 16);
        v.z = (unsigned)tmp[4] | ((unsigned)tmp[5] << 16);
        v.w = (unsigned)tmp[6] | ((unsigned)tmp[7] << 16);
        Ws[f] = v;
    } else {
        int t = threadIdx.x;
        if (t < 64) {
            int isbf = wave_isbf(v1w);
            int n64ok = 1;
#pragma unroll
            for (int i = 0; i < 8; ++i)   // int64 nbr: every odd dword zero
                if (nbrw[2 * (t * 8 + i) + 1] != 0u) n64ok = 0;
            int n64 = __all(n64ok);
            if (t == 0) { flags[0] = isbf; flags[1] = n64; }
        }
        uint4 z = make_uint4(0u, 0u, 0u, 0u);
        if (t >= 64 && t < 72) fbuf[(size_t)NVOX * 8 + (t - 64)] = z;
        if (t >= 72 && t < 80) hbuf[(size_t)NVOX * 8 + (t - 72)] = z;
    }
}

// async-stage tap kk into tile (bp)+(off). Wave w stages ONLY its own group
// (rows 16w..16w+16) and gates on that group's mask bit (wave-uniform).
// Slot s holds logical frag f=(s - s/8)&7 of row s/8 (XOR swizzle via addr);
// destination is wave-uniform base + lane*16 (contiguous per call).
#define STG(kk, bp, off) do {                                               \
    if ((mgw >> (kk)) & 1) {                                                \
        int ia_ = nbrLDS[(kk) * NSTR + r0];                                 \
        int ib_ = nbrLDS[(kk) * NSTR + r1];                                 \
        gload_lds16(srcB + (size_t)ia_ * ROWB + f0 * 16,                    \
                    (void*)((bp) + (off) + w * 128));                       \
        gload_lds16(srcB + (size_t)ib_ * ROWB + f1 * 16,                    \
                    (void*)((bp) + (off) + w * 128 + 64));                  \
    } } while (0)

// B-fragment load for tap kk (clamped: dead prefetch past tap 26 reads tap 26)
#define LOADB(kk, B0, B1) do {                                              \
    int kc_ = (kk) < 26 ? (kk) : 26;                                        \
    B0 = Ws[kc_ * 512 + w * 64 + l];                                        \
    B1 = Ws[kc_ * 512 + 256 + w * 64 + l];                                  \
} while (0)

// MFMAs of tap kk from LDS tile bp, group-gated (wave-uniform scalar branch)
#define COMPUTE(kk, bp, B0, B1) do {                                        \
    _Pragma("unroll")                                                       \
    for (int g = 0; g < 4; ++g) {                                           \
        if ((mg[g] >> (kk)) & 1) {                                          \
            bf16x8 a0_ = *(const bf16x8*)((bp) + ro0[g]);                   \
            bf16x8 a1_ = *(const bf16x8*)((bp) + ro1[g]);                   \
            acc[g] = __builtin_amdgcn_mfma_f32_16x16x32_bf16(a0_, B0, acc[g], 0, 0, 0); \
            acc[g] = __builtin_amdgcn_mfma_f32_16x16x32_bf16(a1_, B1, acc[g], 0, 0, 0); \
        }                                                                   \
    }                                                                       \
} while (0)

// -------- fused sparse-conv + BN (+ residual) + ReLU
// Block: 64 voxels x 64 cout, 4 waves. A staged by async DMA, 2 taps per
// LDS buffer per barrier (15 barriers vs 27), per-group DMA gating.
__global__ __launch_bounds__(256, 4)
void conv_bn_kernel(const uint4* __restrict__ srcV,   // (NVOX+1) x 8 uint4 bf16 rows
                    const void* __restrict__ nbr,
                    const bf16x8* __restrict__ Ws,
                    const void* __restrict__ gg, const void* __restrict__ bb,
                    const void* __restrict__ mm, const void* __restrict__ vv,
                    const u16x8* __restrict__ resid,  // bf16 fbuf rows, null for conv1
                    const int* __restrict__ flags,
                    void* __restrict__ dst, int final_out) {
    __shared__ uint4 sm[459 + 2048];     // nbr(459) + 2 buffers x (2 taps x 512)
    __shared__ int maskLDS[4];
    int*   nbrLDS = (int*)sm;            // [NTAP][NSTR]
    uint4* at0    = sm + 459;            // buffer 0: taps (k, k+1) at off 0 / 512
    uint4* at1    = at0 + 1024;          // buffer 1
    float* outLDS = (float*)sm;          // epilogue alias

    const int tid  = threadIdx.x;
    const int base = blockIdx.x * 64;
    const int isbf = flags[0];
    const int n64  = flags[1];
    const char* srcB = (const char*)srcV;

    if (tid < 4) maskLDS[tid] = 0;
    {   // stage neighbor indices, transposed into LDS
        for (int i = tid; i < NTAP * 64; i += 256) {
            int mvox = i / NTAP;
            int ktap = i - mvox * NTAP;
            long gi = (long)base * NTAP + i;
            int idx = n64 ? (int)((const long long*)nbr)[gi] : ((const int*)nbr)[gi];
            nbrLDS[ktap * NSTR + mvox] = idx;
        }
    }
    __syncthreads();

    // per-(tap, 16-voxel-group) validity bitmask
    if (tid < NTAP * 4) {
        int k = tid >> 2, g = tid & 3;
        const int4* p = (const int4*)&nbrLDS[k * NSTR + g * 16];
        int4 a = p[0], b = p[1], c = p[2], d = p[3];
        int mn = min(min(min(a.x, a.y), min(a.z, a.w)),
                     min(min(min(b.x, b.y), min(b.z, b.w)),
                         min(min(min(c.x, c.y), min(c.z, c.w)),
                             min(min(d.x, d.y), min(d.z, d.w)))));
        if (mn < NVOX) atomicOr(&maskLDS[g], 1 << k);
    }
    __syncthreads();

    const int w = tid >> 6, l = tid & 63;
    const int quad = l >> 4, li = l & 15;

    int mg[4];
#pragma unroll
    for (int g = 0; g < 4; ++g) mg[g] = __builtin_amdgcn_readfirstlane(maskLDS[g]);
    const int mgw = __builtin_amdgcn_readfirstlane(maskLDS[w]);  // staging gate

    // staging geometry: wave w's 2 DMA slots cover rows [16w, 16w+16)
    const int s0 = w * 128 + l;
    const int s1 = s0 + 64;
    const int r0 = s0 >> 3, f0 = (s0 - r0) & 7;
    const int r1 = s1 >> 3, f1 = (s1 - r1) & 7;
    // compute-side fragment read offsets (uint4 units, constant across taps)
    int ro0[4], ro1[4];
#pragma unroll
    for (int g = 0; g < 4; ++g) {
        int row = g * 16 + li;
        ro0[g] = row * 8 + ((quad + row) & 7);
        ro1[g] = row * 8 + ((quad + 4 + row) & 7);
    }

    f32x4 acc[4];
#pragma unroll
    for (int g = 0; g < 4; ++g) acc[g] = (f32x4){0.f, 0.f, 0.f, 0.f};

    bf16x8 xB0, xB1, yB0, yB1;

    STG(0, at0, 0);
    STG(1, at0, 512);
    LOADB(0, xB0, xB1);
    __syncthreads();   // drains DMA -> at0 (taps 0,1) ready

    // taps padded to 28; mask bits >= 27 are zero (self-gating)
    for (int k = 0; k < 28; k += 4) {
        STG(k + 2, at1, 0);
        STG(k + 3, at1, 512);
        LOADB(k + 1, yB0, yB1);
        COMPUTE(k, at0, xB0, xB1);
        LOADB(k + 2, xB0, xB1);
        COMPUTE(k + 1, at0 + 512, yB0, yB1);
        __syncthreads();   // drains -> at1 (taps k+2,k+3) ready
        STG(k + 4, at0, 0);
        STG(k + 5, at0, 512);
        LOADB(k + 3, yB0, yB1);
        COMPUTE(k + 2, at1, xB0, xB1);
        LOADB(k + 4, xB0, xB1);
        COMPUTE(k + 3, at1 + 512, yB0, yB1);
        __syncthreads();   // drains -> at0 (taps k+4,k+5) ready
    }

    // BN into LDS tile (pre-activation), then coalesced writeout
    const int c = w * 16 + li;
    float scale = ld_param(gg, c, isbf) * rsqrtf(ld_param(vv, c, isbf) + 1e-5f);
    float offs  = ld_param(bb, c, isbf) - ld_param(mm, c, isbf) * scale;

#pragma unroll
    for (int g = 0; g < 4; ++g)
#pragma unroll
        for (int r = 0; r < 4; ++r)
            outLDS[(g * 16 + quad * 4 + r) * OSTR + c] = acc[g][r] * scale + offs;
    __syncthreads();

    {   // thread t -> row t>>2, 16-channel chunk t&3 (32 B/lane stores)
        int trow = tid >> 2, cc = tid & 3;
        long grow = base + trow;
        const float4* lp = (const float4*)&outLDS[trow * OSTR + cc * 16];
        float4 q0 = lp[0], q1 = lp[1], q2 = lp[2], q3 = lp[3];
        float vals[16] = {q0.x, q0.y, q0.z, q0.w, q1.x, q1.y, q1.z, q1.w,
                          q2.x, q2.y, q2.z, q2.w, q3.x, q3.y, q3.z, q3.w};

        if (resid) {
            const u16x8* rp = resid + grow * 8 + cc * 2;
            u16x8 r0v = rp[0], r1v = rp[1];
#pragma unroll
            for (int j = 0; j < 8; ++j) { vals[j] += bf2f(r0v[j]); vals[8 + j] += bf2f(r1v[j]); }
        }
#pragma unroll
        for (int j = 0; j < 16; ++j) vals[j] = fmaxf(vals[j], 0.f);

        const int store_bf = (!final_out) || isbf;
        if (store_bf) {
            u16x8 o0, o1;
#pragma unroll
            for (int j = 0; j < 8; ++j) { o0[j] = f2bf_bits(vals[j]); o1[j] = f2bf_bits(vals[8 + j]); }
            u16x8* dp = (u16x8*)dst + grow * 8 + cc * 2;
            dp[0] = o0; dp[1] = o1;
        } else {
            float4* dp = (float4*)dst + grow * 16 + cc * 4;
            dp[0] = (float4){vals[0], vals[1], vals[2], vals[3]};
            dp[1] = (float4){vals[4], vals[5], vals[6], vals[7]};
            dp[2] = (float4){vals[8], vals[9], vals[10], vals[11]};
            dp[3] = (float4){vals[12], vals[13], vals[14], vals[15]};
        }
    }
}

extern "C" void kernel_launch(void* const* d_in, const int* in_sizes, int n_in,
                              void* d_out, int out_size, void* d_ws, size_t ws_size,
                              hipStream_t stream) {
    const void* feats = d_in[0];
    const void* nbr   = d_in[1];
    const void* W1    = d_in[2];
    const void* g1    = d_in[3];
    const void* b1    = d_in[4];
    const void* m1    = d_in[5];
    const void* v1    = d_in[6];
    const void* W2    = d_in[7];
    const void* g2    = d_in[8];
    const void* b2    = d_in[9];
    const void* m2    = d_in[10];
    const void* v2    = d_in[11];

    char* ws = (char*)d_ws;
    uint4* fbuf = (uint4*)(ws + FB_OFF);
    uint4* hbuf = (uint4*)(ws + H_OFF);
    uint4* Ws1  = (uint4*)(ws + WS1_OFF);
    uint4* Ws2  = (uint4*)(ws + WS2_OFF);
    int*   flags = (int*)(ws + FLAG_OFF);

    prep_kernel<<<dim3(6359), dim3(256), 0, stream>>>(
        feats, W1, W2, (const unsigned*)v1, (const unsigned*)nbr,
        fbuf, hbuf, Ws1, Ws2, flags);

    conv_bn_kernel<<<dim3(NVOX / 64), dim3(256), 0, stream>>>(
        fbuf, nbr, (const bf16x8*)Ws1, g1, b1, m1, v1,
        /*resid=*/nullptr, flags, hbuf, /*final_out=*/0);

    conv_bn_kernel<<<dim3(NVOX / 64), dim3(256), 0, stream>>>(
        hbuf, nbr, (const bf16x8*)Ws2, g2, b2, m2, v2,
        /*resid=*/(const u16x8*)fbuf, flags, d_out, /*final_out=*/1);
}

// Round 12
// 241.622 us; speedup vs baseline: 3.8304x; 1.2077x over previous
//
#include <hip/hip_runtime.h>
#include <hip/hip_bf16.h>

#define NVOX 200000
#define NTAP 27
#define OSTR 68   // out LDS row stride (floats)
#define ROWB 128  // bytes per bf16 feature row (64 ch)

typedef __bf16          bf16x8 __attribute__((ext_vector_type(8)));
typedef unsigned short  u16x8  __attribute__((ext_vector_type(8)));
typedef float           f32x4  __attribute__((ext_vector_type(4)));

// ws layout (bytes). fbuf/hbuf have NVOX+1 rows; row NVOX is the zero
// sentinel so gathers are branchless.
#define FB_BYTES    ((size_t)(NVOX + 1) * ROWB)      // 25,600,128
#define WSHUF_BYTES (NTAP * 2 * 4 * 64 * 16)         // 221,184 per conv
#define FB_OFF      0
#define H_OFF       (FB_BYTES)
#define WS1_OFF     (2 * FB_BYTES)
#define WS2_OFF     (WS1_OFF + WSHUF_BYTES)
#define FLAG_OFF    (WS2_OFF + WSHUF_BYTES)

static __device__ __forceinline__ unsigned short f2bf_bits(float f) {
    __hip_bfloat16 h = __float2bfloat16(f);
    union { __hip_bfloat16 h; unsigned short u; } u; u.h = h; return u.u;
}
static __device__ __forceinline__ float bf2f(unsigned short s) {
    union { float f; unsigned u; } u; u.u = ((unsigned)s) << 16; return u.f;
}
static __device__ __forceinline__ float ld_param(const void* p, int c, int isbf) {
    return isbf ? bf2f(((const unsigned short*)p)[c]) : ((const float*)p)[c];
}
// async DMA: 16 B from global (per-lane addr) -> LDS (wave-uniform base + lane*16)
static __device__ __forceinline__ void gload_lds16(const void* gp, void* lp) {
    __builtin_amdgcn_global_load_lds(
        (const __attribute__((address_space(1))) void*)gp,
        (__attribute__((address_space(3))) void*)lp, 16, 0, 0);
}
// wave-uniform: are float tensors packed bf16? (v1 in [0.5,1.5] -> 0x3F00..0x3FC0)
static __device__ __forceinline__ int wave_isbf(const unsigned* v1w) {
    int l = threadIdx.x & 63;
    int ok = 1;
    if (l < 32) {
        unsigned w = v1w[l], lo = w & 0xFFFFu, hi = w >> 16;
        ok = (lo >= 0x3F00u && lo <= 0x3FC0u && hi >= 0x3F00u && hi <= 0x3FC0u);
    }
    return __all(ok);
}

// -------- mega-prep: feats->bf16 fbuf (blocks 0..6249), W-shuffle
// (6250..6357), flags + sentinel-row zeroing (6358)
__global__ __launch_bounds__(256)
void prep_kernel(const void* __restrict__ feats,
                 const void* __restrict__ W1, const void* __restrict__ W2,
                 const unsigned* __restrict__ v1w, const unsigned* __restrict__ nbrw,
                 uint4* __restrict__ fbuf, uint4* __restrict__ hbuf,
                 uint4* __restrict__ Ws1, uint4* __restrict__ Ws2,
                 int* __restrict__ flags) {
    const int bx = blockIdx.x;
    if (bx < 6250) {
        const int isbf = wave_isbf(v1w);
        size_t t = (size_t)bx * 256 + threadIdx.x;   // fragment id (16 B)
        if (isbf) {
            fbuf[t] = ((const uint4*)feats)[t];
        } else {
            float4 a = ((const float4*)feats)[2 * t];
            float4 b = ((const float4*)feats)[2 * t + 1];
            union { uint4 q; unsigned short u[8]; } o;
            o.u[0] = f2bf_bits(a.x); o.u[1] = f2bf_bits(a.y);
            o.u[2] = f2bf_bits(a.z); o.u[3] = f2bf_bits(a.w);
            o.u[4] = f2bf_bits(b.x); o.u[5] = f2bf_bits(b.y);
            o.u[6] = f2bf_bits(b.z); o.u[7] = f2bf_bits(b.w);
            fbuf[t] = o.q;
        }
    } else if (bx < 6358) {
        const int isbf = wave_isbf(v1w);
        int t = (bx - 6250) * 256 + threadIdx.x;     // < 27648
        const void* W = (t < 13824) ? W1 : W2;
        uint4* Ws     = (t < 13824) ? Ws1 : Ws2;
        int f = (t < 13824) ? t : t - 13824;
        int k  = f / 512;
        int r  = f % 512;
        int kc = r / 256;
        int r2 = r % 256;
        int nc = r2 / 64;
        int l  = r2 % 64;
        int quad = l >> 4, li = l & 15;
        unsigned short tmp[8];
#pragma unroll
        for (int j = 0; j < 8; ++j) {
            int off = k * 4096 + (kc * 32 + quad * 8 + j) * 64 + (nc * 16 + li);
            tmp[j] = isbf ? ((const unsigned short*)W)[off]
                          : f2bf_bits(((const float*)W)[off]);
        }
        uint4 v;
        v.x = (unsigned)tmp[0] | ((unsigned)tmp[1] << 16);
        v.y = (unsigned)tmp[2] | ((unsigned)tmp[3] << 16);
        v.z = (unsigned)tmp[4] | ((unsigned)tmp[5] << 16);
        v.w = (unsigned)tmp[6] | ((unsigned)tmp[7] << 16);
        Ws[f] = v;
    } else {
        int t = threadIdx.x;
        if (t < 64) {
            int isbf = wave_isbf(v1w);
            int n64ok = 1;
#pragma unroll
            for (int i = 0; i < 8; ++i)   // int64 nbr: every odd dword zero
                if (nbrw[2 * (t * 8 + i) + 1] != 0u) n64ok = 0;
            int n64 = __all(n64ok);
            if (t == 0) { flags[0] = isbf; flags[1] = n64; }
        }
        uint4 z = make_uint4(0u, 0u, 0u, 0u);
        if (t >= 64 && t < 72) fbuf[(size_t)NVOX * 8 + (t - 64)] = z;
        if (t >= 72 && t < 80) hbuf[(size_t)NVOX * 8 + (t - 72)] = z;
    }
}

// async-stage tap kk's rows for THIS wave's group (rows 16w..16w+16), gated
// on this group's mask bit (wave-uniform). nbr layout is [vox][tap] (stride
// 27). Slot s holds logical frag f=(s - s/8)&7 of row s/8 (XOR swizzle via
// the gathered address); LDS dest is wave-uniform base + lane*16.
#define STG(kk, bp) do {                                                    \
    if ((mgw >> (kk)) & 1) {                                                \
        int ia_ = nbrLDS[r0 * NTAP + (kk)];                                 \
        int ib_ = nbrLDS[r1 * NTAP + (kk)];                                 \
        gload_lds16(srcB + (size_t)ia_ * ROWB + f0 * 16,                    \
                    (void*)((bp) + w * 128));                               \
        gload_lds16(srcB + (size_t)ib_ * ROWB + f1 * 16,                    \
                    (void*)((bp) + w * 128 + 64));                         \
    } } while (0)

#define LOADB(kk, B0, B1) do {                                              \
    B0 = Ws[(kk) * 512 + w * 64 + l];                                       \
    B1 = Ws[(kk) * 512 + 256 + w * 64 + l];                                 \
} while (0)

// MFMAs of tap kk from LDS tile bp, group-gated (wave-uniform scalar branch)
#define COMPUTE(kk, bp, B0, B1) do {                                        \
    _Pragma("unroll")                                                       \
    for (int g = 0; g < 4; ++g) {                                           \
        if ((mg[g] >> (kk)) & 1) {                                          \
            bf16x8 a0_ = *(const bf16x8*)((bp) + ro0[g]);                   \
            bf16x8 a1_ = *(const bf16x8*)((bp) + ro1[g]);                   \
            acc[g] = __builtin_amdgcn_mfma_f32_16x16x32_bf16(a0_, B0, acc[g], 0, 0, 0); \
            acc[g] = __builtin_amdgcn_mfma_f32_16x16x32_bf16(a1_, B1, acc[g], 0, 0, 0); \
        }                                                                   \
    }                                                                       \
} while (0)

// -------- fused sparse-conv + BN (+ residual) + ReLU
// Block: 64 voxels x 64 cout, 4 waves. A staged by async DMA (1 tap per
// buffer, double-buffered, 27 barriers — R7 structure), per-wave DMA gating.
// LDS trimmed to 23.3 KB -> targets 7 blocks/CU.
__global__ __launch_bounds__(256, 7)
void conv_bn_kernel(const uint4* __restrict__ srcV,   // (NVOX+1) x 8 uint4 bf16 rows
                    const void* __restrict__ nbr,
                    const bf16x8* __restrict__ Ws,
                    const void* __restrict__ gg, const void* __restrict__ bb,
                    const void* __restrict__ mm, const void* __restrict__ vv,
                    const u16x8* __restrict__ resid,  // bf16 fbuf rows, null for conv1
                    const int* __restrict__ flags,
                    void* __restrict__ dst, int final_out) {
    // smi: nbr [64][27] ints (0..1727) | A-tiles 2x512 uint4 at int-ofs 1728
    // (byte 6912, 16B-aligned) | mask at 5824. Epilogue outLDS aliases smi.
    __shared__ __align__(16) int smi[5828];
    int*   nbrLDS = smi;
    uint4* at0    = (uint4*)(smi + 1728);
    uint4* at1    = at0 + 512;
    int*   maskLDS = smi + 5824;
    float* outLDS = (float*)smi;

    const int tid  = threadIdx.x;
    const int base = blockIdx.x * 64;
    const int isbf = flags[0];
    const int n64  = flags[1];
    const char* srcB = (const char*)srcV;

    if (tid < 4) maskLDS[tid] = 0;
    __syncthreads();
    {   // stage neighbor indices: natural [vox][tap] layout, pure coalesced copy
        if (!n64) {
            const int* np = (const int*)nbr + (long)base * NTAP;
            for (int i = tid; i < 64 * NTAP; i += 256) nbrLDS[i] = np[i];
        } else {
            const long long* np = (const long long*)nbr + (long)base * NTAP;
            for (int i = tid; i < 64 * NTAP; i += 256) nbrLDS[i] = (int)np[i];
        }
    }
    __syncthreads();

    // per-(tap, 16-voxel-group) validity bitmask
    if (tid < NTAP * 4) {
        int k = tid >> 2, g = tid & 3;
        int mn = 0x7fffffff;
#pragma unroll
        for (int r = 0; r < 16; ++r) mn = min(mn, nbrLDS[(g * 16 + r) * NTAP + k]);
        if (mn < NVOX) atomicOr(&maskLDS[g], 1 << k);
    }
    __syncthreads();

    const int w = tid >> 6, l = tid & 63;
    const int quad = l >> 4, li = l & 15;

    int mg[4];
#pragma unroll
    for (int g = 0; g < 4; ++g) mg[g] = __builtin_amdgcn_readfirstlane(maskLDS[g]);
    const int mgw = __builtin_amdgcn_readfirstlane(maskLDS[w]);  // staging gate

    // staging geometry: wave w's 2 DMA slots cover rows [16w, 16w+16)
    const int s0 = w * 128 + l;
    const int s1 = s0 + 64;
    const int r0 = s0 >> 3, f0 = (s0 - r0) & 7;
    const int r1 = s1 >> 3, f1 = (s1 - r1) & 7;
    // compute-side fragment read offsets (uint4 units, constant across taps)
    int ro0[4], ro1[4];
#pragma unroll
    for (int g = 0; g < 4; ++g) {
        int row = g * 16 + li;
        ro0[g] = row * 8 + ((quad + row) & 7);
        ro1[g] = row * 8 + ((quad + 4 + row) & 7);
    }

    f32x4 acc[4];
#pragma unroll
    for (int g = 0; g < 4; ++g) acc[g] = (f32x4){0.f, 0.f, 0.f, 0.f};

    bf16x8 xB0, xB1, yB0, yB1;

    STG(0, at0);
    LOADB(0, xB0, xB1);
    __syncthreads();   // drains DMA -> at0 (tap 0) ready

    for (int k = 0; k < 26; k += 2) {
        STG(k + 1, at1);
        LOADB(k + 1, yB0, yB1);
        COMPUTE(k, at0, xB0, xB1);
        __syncthreads();   // drains -> at1 (tap k+1) ready
        STG(k + 2, at0);   // k+2 <= 26 (k <= 24)
        LOADB(k + 2, xB0, xB1);
        COMPUTE(k + 1, at1, yB0, yB1);
        __syncthreads();   // drains -> at0 (tap k+2) ready
    }
    COMPUTE(26, at0, xB0, xB1);

    // BN into LDS tile (pre-activation), then coalesced writeout
    const int c = w * 16 + li;
    float scale = ld_param(gg, c, isbf) * rsqrtf(ld_param(vv, c, isbf) + 1e-5f);
    float offs  = ld_param(bb, c, isbf) - ld_param(mm, c, isbf) * scale;

    __syncthreads();   // all waves done with tiles (outLDS aliases them)
#pragma unroll
    for (int g = 0; g < 4; ++g)
#pragma unroll
        for (int r = 0; r < 4; ++r)
            outLDS[(g * 16 + quad * 4 + r) * OSTR + c] = acc[g][r] * scale + offs;
    __syncthreads();

    {   // thread t -> row t>>2, 16-channel chunk t&3 (32 B/lane stores)
        int trow = tid >> 2, cc = tid & 3;
        long grow = base + trow;
        const float4* lp = (const float4*)&outLDS[trow * OSTR + cc * 16];
        float4 q0 = lp[0], q1 = lp[1], q2 = lp[2], q3 = lp[3];
        float vals[16] = {q0.x, q0.y, q0.z, q0.w, q1.x, q1.y, q1.z, q1.w,
                          q2.x, q2.y, q2.z, q2.w, q3.x, q3.y, q3.z, q3.w};

        if (resid) {
            const u16x8* rp = resid + grow * 8 + cc * 2;
            u16x8 r0v = rp[0], r1v = rp[1];
#pragma unroll
            for (int j = 0; j < 8; ++j) { vals[j] += bf2f(r0v[j]); vals[8 + j] += bf2f(r1v[j]); }
        }
#pragma unroll
        for (int j = 0; j < 16; ++j) vals[j] = fmaxf(vals[j], 0.f);

        const int store_bf = (!final_out) || isbf;
        if (store_bf) {
            u16x8 o0, o1;
#pragma unroll
            for (int j = 0; j < 8; ++j) { o0[j] = f2bf_bits(vals[j]); o1[j] = f2bf_bits(vals[8 + j]); }
            u16x8* dp = (u16x8*)dst + grow * 8 + cc * 2;
            dp[0] = o0; dp[1] = o1;
        } else {
            float4* dp = (float4*)dst + grow * 16 + cc * 4;
            dp[0] = (float4){vals[0], vals[1], vals[2], vals[3]};
            dp[1] = (float4){vals[4], vals[5], vals[6], vals[7]};
            dp[2] = (float4){vals[8], vals[9], vals[10], vals[11]};
            dp[3] = (float4){vals[12], vals[13], vals[14], vals[15]};
        }
    }
}

extern "C" void kernel_launch(void* const* d_in, const int* in_sizes, int n_in,
                              void* d_out, int out_size, void* d_ws, size_t ws_size,
                              hipStream_t stream) {
    const void* feats = d_in[0];
    const void* nbr   = d_in[1];
    const void* W1    = d_in[2];
    const void* g1    = d_in[3];
    const void* b1    = d_in[4];
    const void* m1    = d_in[5];
    const void* v1    = d_in[6];
    const void* W2    = d_in[7];
    const void* g2    = d_in[8];
    const void* b2    = d_in[9];
    const void* m2    = d_in[10];
    const void* v2    = d_in[11];

    char* ws = (char*)d_ws;
    uint4* fbuf = (uint4*)(ws + FB_OFF);
    uint4* hbuf = (uint4*)(ws + H_OFF);
    uint4* Ws1  = (uint4*)(ws + WS1_OFF);
    uint4* Ws2  = (uint4*)(ws + WS2_OFF);
    int*   flags = (int*)(ws + FLAG_OFF);

    prep_kernel<<<dim3(6359), dim3(256), 0, stream>>>(
        feats, W1, W2, (const unsigned*)v1, (const unsigned*)nbr,
        fbuf, hbuf, Ws1, Ws2, flags);

    conv_bn_kernel<<<dim3(NVOX / 64), dim3(256), 0, stream>>>(
        fbuf, nbr, (const bf16x8*)Ws1, g1, b1, m1, v1,
        /*resid=*/nullptr, flags, hbuf, /*final_out=*/0);

    conv_bn_kernel<<<dim3(NVOX / 64), dim3(256), 0, stream>>>(
        hbuf, nbr, (const bf16x8*)Ws2, g2, b2, m2, v2,
        /*resid=*/(const u16x8*)fbuf, flags, d_out, /*final_out=*/1);
}